// Round 5
// baseline (287.171 us; speedup 1.0000x reference)
//
#include <hip/hip_runtime.h>
#include <hip/hip_bf16.h>

#define B_TOT   16384
#define D_IN    784
#define H_DIM   100
#define C_DIM   10
#define HP      128
#define KP      832     // 13 * 64, padded K
#define NDR     13
#define WG_ROWS 16

typedef __bf16 bf16x8 __attribute__((ext_vector_type(8)));
typedef float  f32x4  __attribute__((ext_vector_type(4)));
typedef unsigned short u16x8 __attribute__((ext_vector_type(8)));

static __device__ __forceinline__ unsigned short f32_to_bf16(float f) {
    unsigned int u = __float_as_uint(f);
    unsigned int r = (u + 0x7FFFu + ((u >> 16) & 1u)) >> 16;
    return (unsigned short)r;
}

__global__ void prep_kernel(const float* __restrict__ W1, const float* __restrict__ b1,
                            unsigned short* __restrict__ w1hi, unsigned short* __restrict__ w1lo,
                            float* __restrict__ b1p) {
    int idx = blockIdx.x * 256 + threadIdx.x;
    if (idx < HP) b1p[idx] = (idx < H_DIM) ? b1[idx] : 0.0f;
    if (idx < HP * KP) {
        int h = idx / KP, k = idx - h * KP;
        float v = (h < H_DIM && k < D_IN) ? W1[h * D_IN + k] : 0.0f;
        unsigned short hi = f32_to_bf16(v);
        float fh = __uint_as_float(((unsigned int)hi) << 16);
        unsigned short lo = f32_to_bf16(v - fh);
        w1hi[idx] = hi;
        w1lo[idx] = lo;
    }
}

// spike pack: bit-identical arithmetic to the passing round-1 kernel
static __device__ __forceinline__ u16x8 spike8(const f32x4 i0, const f32x4 i1,
                                               const f32x4 r0, const f32x4 r1) {
    float xs[8] = {i0[0],i0[1],i0[2],i0[3],i1[0],i1[1],i1[2],i1[3]};
    float rs[8] = {r0[0],r0[1],r0[2],r0[3],r1[0],r1[1],r1[2],r1[3]};
    u16x8 v;
#pragma unroll
    for (int j = 0; j < 8; ++j) {
        unsigned short sg = xs[j] > 0.0f ? (unsigned short)0x3F80
                          : (xs[j] < 0.0f ? (unsigned short)0xBF80 : (unsigned short)0);
        v[j] = (rs[j] * 2.0f <= fabsf(xs[j])) ? sg : (unsigned short)0;
    }
    return v;
}

// Light kernel: 16-row WGs, 1024 WGs (4/CU), 2-timestep passes, state in regs.
__global__ __launch_bounds__(256, 4)
void snn_main(const float* __restrict__ inp, const float* __restrict__ rnd,
              const unsigned short* __restrict__ w1hi, const unsigned short* __restrict__ w1lo,
              const float* __restrict__ b1p, const float* __restrict__ W2,
              const float* __restrict__ b2, float* __restrict__ out)
{
    __shared__ __align__(16) unsigned short s_spike[2 * WG_ROWS * 64]; // 4 KB: [tt][16][64] swizzled
    __shared__ float s_cnt[WG_ROWS][HP];                               // 8 KB

    const int tid  = threadIdx.x;
    const int lane = tid & 63;
    const int wid  = tid >> 6;
    const int n_off = wid * 32;          // each wave owns 32 output cols
    const int row0 = blockIdx.x * WG_ROWS;

    const int l15 = lane & 15;
    const int l4  = lane >> 4;

    // staging mapping: 256 threads -> (tthalf, row, 8-col granule)
    const int tthalf = tid >> 7;         // 0..1
    const int sr  = (tid >> 3) & 15;     // 0..15
    const int scg = tid & 7;             // 0..7
    const size_t inp_base = (size_t)(row0 + sr) * D_IN;
    const int swByte = ((tthalf * WG_ROWS + sr) * 8 + (scg ^ (sr & 7))) * 16;
    const size_t BD = (size_t)B_TOT * D_IN;

    float b1v[2];
#pragma unroll
    for (int nt = 0; nt < 2; ++nt) b1v[nt] = b1p[n_off + nt * 16 + l15];

    f32x4 mem1[2], cnt[2];
#pragma unroll
    for (int nt = 0; nt < 2; ++nt) { mem1[nt] = (f32x4)0.0f; cnt[nt] = (f32x4)0.0f; }

    for (int tp = 0; tp < 4; ++tp) {     // 4 passes x 2 timesteps
        f32x4 acc[2][2];                 // [tt][nt]
#pragma unroll
        for (int a_ = 0; a_ < 2; ++a_)
#pragma unroll
            for (int b_ = 0; b_ < 2; ++b_) acc[a_][b_] = (f32x4)0.0f;

        for (int dr = 0; dr < NDR; ++dr) {
            const int kbase = dr * 64;
            // ---- stage spikes for 2 timesteps (each thread: 1 granule of 1 tt) ----
            const int gd = kbase + scg * 8;
            u16x8 v = (u16x8)0;
            if (gd + 8 <= D_IN) {
                const f32x4* ip = reinterpret_cast<const f32x4*>(inp + inp_base + gd);
                const f32x4* rp = reinterpret_cast<const f32x4*>(
                    rnd + (size_t)(tp * 2 + tthalf) * BD + inp_base + gd);
                f32x4 i0 = ip[0], i1 = ip[1];
                f32x4 r0 = __builtin_nontemporal_load(rp);
                f32x4 r1 = __builtin_nontemporal_load(rp + 1);
                v = spike8(i0, i1, r0, r1);
            }
            __syncthreads();   // previous round's reads done
            *reinterpret_cast<u16x8*>(reinterpret_cast<char*>(s_spike) + swByte) = v;
            __syncthreads();   // spikes visible

            // ---- MFMA: c-chunked B loads (short live ranges) ----
#pragma unroll
            for (int c = 0; c < 2; ++c) {
                bf16x8 bh[2], blo[2];
#pragma unroll
                for (int nt = 0; nt < 2; ++nt) {
                    int off = (n_off + nt * 16 + l15) * KP + kbase + c * 32 + l4 * 8;
                    bh[nt]  = *reinterpret_cast<const bf16x8*>(w1hi + off);
                    blo[nt] = *reinterpret_cast<const bf16x8*>(w1lo + off);
                }
                const int g = (c * 4 + l4) ^ (l15 & 7);
#pragma unroll
                for (int tt = 0; tt < 2; ++tt) {
                    bf16x8 a = *reinterpret_cast<const bf16x8*>(
                        reinterpret_cast<const char*>(s_spike) +
                        (tt * WG_ROWS + l15) * 128 + g * 16);
#pragma unroll
                    for (int nt = 0; nt < 2; ++nt) {
                        acc[tt][nt] = __builtin_amdgcn_mfma_f32_16x16x32_bf16(a, bh[nt],  acc[tt][nt], 0, 0, 0);
                        acc[tt][nt] = __builtin_amdgcn_mfma_f32_16x16x32_bf16(a, blo[nt], acc[tt][nt], 0, 0, 0);
                    }
                }
            }
        }

        // ---- sequential mem1 update for the 2 timesteps of this pass ----
#pragma unroll
        for (int tt = 0; tt < 2; ++tt)
#pragma unroll
            for (int nt = 0; nt < 2; ++nt)
#pragma unroll
                for (int r = 0; r < 4; ++r) {
                    float m = 0.95f * mem1[nt][r] + acc[tt][nt][r];
                    m = m + b1v[nt];
                    float o = (m > 1.0f) ? 1.0f : 0.0f;
                    mem1[nt][r] = m - o;
                    cnt[nt][r] += o;
                }
    }

    // ---- epilogue: counts -> LDS -> layer-2 matmul ----
    __syncthreads();
#pragma unroll
    for (int nt = 0; nt < 2; ++nt)
#pragma unroll
        for (int r = 0; r < 4; ++r)
            s_cnt[l4 * 4 + r][n_off + nt * 16 + l15] = cnt[nt][r];
    __syncthreads();
    for (int idx = tid; idx < WG_ROWS * C_DIM; idx += 256) {
        int bl_ = idx / C_DIM, c_ = idx - bl_ * C_DIM;
        float s_ = 0.0f;
        for (int h_ = 0; h_ < H_DIM; ++h_) s_ += s_cnt[bl_][h_] * W2[c_ * H_DIM + h_];
        out[(size_t)(row0 + bl_) * C_DIM + c_] = s_ * 0.125f + b2[c_];
    }
}

extern "C" void kernel_launch(void* const* d_in, const int* in_sizes, int n_in,
                              void* d_out, int out_size, void* d_ws, size_t ws_size,
                              hipStream_t stream) {
    const float* inp = (const float*)d_in[0];
    const float* rnd = (const float*)d_in[1];
    const float* W1  = (const float*)d_in[2];
    const float* b1  = (const float*)d_in[3];
    const float* W2  = (const float*)d_in[4];
    const float* b2  = (const float*)d_in[5];
    float* out = (float*)d_out;

    unsigned short* w1hi = (unsigned short*)d_ws;
    unsigned short* w1lo = w1hi + HP * KP;
    float* b1p = (float*)(w1lo + HP * KP);

    prep_kernel<<<(HP * KP + 255) / 256, 256, 0, stream>>>(W1, b1, w1hi, w1lo, b1p);
    snn_main<<<B_TOT / WG_ROWS, 256, 0, stream>>>(inp, rnd, w1hi, w1lo, b1p, W2, b2, out);
}